// Round 7
// baseline (538.713 us; speedup 1.0000x reference)
//
#include <hip/hip_runtime.h>

typedef __attribute__((ext_vector_type(4))) float f32x4;
typedef __attribute__((ext_vector_type(16))) float f32x16;
typedef __attribute__((ext_vector_type(4))) unsigned short u16x4;
typedef __attribute__((ext_vector_type(4))) int i32x4;
typedef __attribute__((ext_vector_type(8))) __bf16 bf16x8;

union FragAB {
  u16x4 u[2];
  i32x4 v;
  bf16x8 f;
};

static __device__ __forceinline__ unsigned short f2bf(float x) {
  union { float f; unsigned u; } v;
  v.f = x;
  unsigned r = v.u + 0x7FFFu + ((v.u >> 16) & 1u);  // round-to-nearest-even
  return (unsigned short)(r >> 16);
}

#define NN 8192

// ---------- kernel 1: prep (unchanged, verified) ----------
__global__ __launch_bounds__(256) void k_prep(
    const int* __restrict__ adj, const float* __restrict__ V,
    const float* __restrict__ w1, const float* __restrict__ w2,
    const float* __restrict__ w3, const float* __restrict__ bias,
    unsigned char* __restrict__ adj2b, unsigned short* __restrict__ Vbp,
    unsigned short* __restrict__ Wbp, float* __restrict__ out) {
  int t = blockIdx.x * 256 + threadIdx.x;
  int nT = gridDim.x * 256;
  for (int g = t; g < 16777216; g += nT) {
    i32x4 a = *(const i32x4*)(adj + (size_t)g * 4);
    adj2b[g] = (unsigned char)((a.x & 3) | ((a.y & 3) << 2) |
                               ((a.z & 3) << 4) | ((a.w & 3) << 6));
  }
  for (int g = t; g < 524288; g += nT) {
    int f = g * 4;
    int row = f >> 8, kcol = f & 255;
    f32x4 x = *(const f32x4*)(V + (size_t)f);
    u16x4 h;
    h.x = f2bf(x.x); h.y = f2bf(x.y); h.z = f2bf(x.z); h.w = f2bf(x.w);
    *(u16x4*)(Vbp + (size_t)(kcol >> 3) * 65536 + (size_t)row * 8 + (kcol & 7)) = h;
  }
  for (int e = t; e < 65536; e += nT) {
    int k = e >> 8, n = e & 255;
    Wbp[(size_t)(k >> 3) * 6144 + (size_t)(0 * 256 + n) * 8 + (k & 7)] = f2bf(w1[e]);
  }
  for (int e = t; e < 65536; e += nT) {
    int k = e >> 8, n = e & 255;
    Wbp[(size_t)(k >> 3) * 6144 + (size_t)(1 * 256 + n) * 8 + (k & 7)] = f2bf(w2[e]);
  }
  for (int e = t; e < 65536; e += nT) {
    int k = e >> 8, n = e & 255;
    Wbp[(size_t)(k >> 3) * 6144 + (size_t)(2 * 256 + n) * 8 + (k & 7)] = f2bf(w3[e]);
  }
  for (int g = t; g < 524288; g += nT) {
    *(f32x4*)(out + (size_t)g * 4) = *(const f32x4*)(bias + ((g * 4) & 255));
  }
}

// ---------- kernel 2: Bp = (V @ Wcat)^T, reg GEMM (unchanged, verified) ----------
// Bp element (ty, n, j) at  ty*2097152 + (j>>4)*4096 + n*16 + (j&15).
__global__ __launch_bounds__(256) void k_transform(
    const unsigned short* __restrict__ Vbp, const unsigned short* __restrict__ Wbp,
    unsigned short* __restrict__ Bp) {
  int bx = blockIdx.x;
  int rb = bx & 127, nb = bx >> 7;
  int tid = threadIdx.x, lane = tid & 63;
  int wv = tid >> 6;
  int wr = wv >> 1, wc = wv & 1;
  int q = lane >> 4, l16 = lane & 15;

  f32x4 acc[2][4];
#pragma unroll
  for (int i = 0; i < 2; i++)
#pragma unroll
    for (int j = 0; j < 4; j++) acc[i][j] = (f32x4)0.0f;

  int r0 = rb * 64 + wr * 32 + l16;
  int n0 = nb * 128 + wc * 64 + l16;
  const unsigned short* av = Vbp + (size_t)q * 65536 + (size_t)r0 * 8;
  const unsigned short* bv = Wbp + (size_t)q * 6144 + (size_t)n0 * 8;

#pragma unroll 2
  for (int kk = 0; kk < 256; kk += 32) {
    FragAB af[2], bf[4];
#pragma unroll
    for (int mt = 0; mt < 2; mt++)
      af[mt].v = *(const i32x4*)(av + (size_t)(kk >> 3) * 65536 + mt * 128);
#pragma unroll
    for (int nt = 0; nt < 4; nt++)
      bf[nt].v = *(const i32x4*)(bv + (size_t)(kk >> 3) * 6144 + nt * 128);
#pragma unroll
    for (int mt = 0; mt < 2; mt++)
#pragma unroll
      for (int nt = 0; nt < 4; nt++)
        acc[mt][nt] = __builtin_amdgcn_mfma_f32_16x16x32_bf16(
            af[mt].f, bf[nt].f, acc[mt][nt], 0, 0, 0);
  }
#pragma unroll
  for (int mt = 0; mt < 2; mt++)
#pragma unroll
    for (int nt = 0; nt < 4; nt++) {
      int n = n0 + nt * 16;
      int ty = n >> 8, nn = n & 255;
      int j0 = rb * 64 + wr * 32 + mt * 16 + q * 4;
      u16x4 hv;
      hv.x = f2bf(acc[mt][nt].x);
      hv.y = f2bf(acc[mt][nt].y);
      hv.z = f2bf(acc[mt][nt].z);
      hv.w = f2bf(acc[mt][nt].w);
      size_t idx = (size_t)ty * 2097152 + (size_t)(j0 >> 4) * 4096 + nn * 16 + (j0 & 15);
      *(u16x4*)(Bp + idx) = hv;
    }
}

// ---------- kernel 3: out += sum_k (adj==k) @ H_k ----------
// v8: LDS-shared B with NO cross-wave read duplication and a conflict-free
// padded layout. Wave = 128 rows x 64 cols (mt=4, nt=2); each B fragment is
// read by exactly ONE wave -> LDS reads/CU/step = 48 KB (was 192 in v7).
// ldsB rows padded to 48 B -> ds_read/ds_write slot = (3n+q)%8 uniform
// (minimum aliasing, no conflicts). BK=16/step, 64 steps, double-buffered
// (72 KB LDS), one barrier per step, reg-staged (T14: loads issued at step
// start, consumed by ds_write after compute). Per-SIMD pipe budget/step:
// MFMA 1550 cyc (critical), mask-VALU ~1150 (co-issued), LDS ~580.
// Grid 64 rb x 8 ks = 512 blocks (2/CU); ks = bx&7 -> per-XCD L2 k-slice.
__global__ __launch_bounds__(256, 2) void k_agg(const unsigned* __restrict__ adj2,
                                                const unsigned short* __restrict__ Bp,
                                                float* __restrict__ out) {
  int bx = blockIdx.x;
  int ks = bx & 7, rb = bx >> 3;
  int tid = threadIdx.x, lane = tid & 63;
  int wn = tid >> 6;  // 0..3: 64-col slab
  int q = lane >> 5, l32 = lane & 31;
  int qsh = q << 4;

  __shared__ unsigned short ldsB[2][3][256][24];  // 24 shorts = 48B padded row

  f32x16 acc[4][2];
#pragma unroll
  for (int mt = 0; mt < 4; mt++)
#pragma unroll
    for (int nt = 0; nt < 2; nt++) acc[mt][nt] = (f32x16)0.0f;

  // adj2 streams: slab mt row = rb*128 + mt*32 + l32 -> +mt*16384 dwords
  const unsigned* ap = adj2 + (size_t)(rb * 128 + l32) * 512 + ks * 64;

  // staging: 24KB/step = 3ty x 8KB contiguous; thread chunk c (ty=c>>1,
  // half=c&1): 16B at image byte half*4096 + tid*16 -> (n = half*128+tid/2,
  // h = tid&1); LDS dst ldsB[buf][ty][n][h*8].
  const char* Bpb = (const char*)Bp;
  const char* sp[6];
#pragma unroll
  for (int c = 0; c < 6; c++)
    sp[c] = Bpb + (size_t)(c >> 1) * 4194304 + (size_t)ks * 524288 +
            (size_t)(c & 1) * 4096 + (size_t)tid * 16;

#define AGG_MT(CC, MT, BV0, BV1, HI)                                           \
  {                                                                            \
    unsigned w = (unsigned)(HI ? (CC >> 32) : CC) >> qsh;                      \
    FragAB A;                                                                  \
    _Pragma("unroll") for (int d = 0; d < 4; d++) {                            \
      unsigned p0 = (w >> (4 * d)) & 3u, p1 = (w >> (4 * d + 2)) & 3u;         \
      A.v[d] = (int)((p0 == ty1 ? 0x3F80u : 0u) |                              \
                     (p1 == ty1 ? 0x3F800000u : 0u));                          \
    }                                                                          \
    acc[MT][0] = __builtin_amdgcn_mfma_f32_32x32x16_bf16(A.f, BV0.f,           \
                                                         acc[MT][0], 0, 0, 0); \
    acc[MT][1] = __builtin_amdgcn_mfma_f32_32x32x16_bf16(A.f, BV1.f,           \
                                                         acc[MT][1], 0, 0, 0); \
  }

#define AGG_TY(BUF, TY, HI)                                                    \
  {                                                                            \
    const unsigned ty1 = TY + 1;                                               \
    FragAB bv0, bv1;                                                           \
    bv0.v = *(const i32x4*)&ldsB[BUF][TY][wn * 64 + l32][q * 8];               \
    bv1.v = *(const i32x4*)&ldsB[BUF][TY][wn * 64 + 32 + l32][q * 8];          \
    AGG_MT(cc0, 0, bv0, bv1, HI)                                               \
    AGG_MT(cc1, 1, bv0, bv1, HI)                                               \
    AGG_MT(cc2, 2, bv0, bv1, HI)                                               \
    AGG_MT(cc3, 3, bv0, bv1, HI)                                               \
  }

#define AGG_STEP(BUF, HI)                                                      \
  AGG_TY(BUF, 0, HI) AGG_TY(BUF, 1, HI) AGG_TY(BUF, 2, HI)

#define AGG_STAGE_WRITE(BUF)                                                   \
  _Pragma("unroll") for (int c = 0; c < 6; c++)                                \
      *(i32x4*)&ldsB[BUF][c >> 1][(c & 1) * 128 + (tid >> 1)][(tid & 1) * 8] = \
          rg[c];

  // prologue: stage step 0 into buf0; load code-pair 0
  i32x4 rg[6];
#pragma unroll
  for (int c = 0; c < 6; c++) rg[c] = *(const i32x4*)sp[c];
  AGG_STAGE_WRITE(0)
  unsigned long long cc0 = *(const unsigned long long*)(ap);
  unsigned long long cc1 = *(const unsigned long long*)(ap + 16384);
  unsigned long long cc2 = *(const unsigned long long*)(ap + 32768);
  unsigned long long cc3 = *(const unsigned long long*)(ap + 49152);
  __syncthreads();

  for (int p = 0; p < 32; ++p) {
    unsigned long long nx0 = 0, nx1 = 0, nx2 = 0, nx3 = 0;
    if (p < 31) {  // next code-pair (2 steps of 16 codes per slab)
      nx0 = *(const unsigned long long*)(ap + (p + 1) * 2);
      nx1 = *(const unsigned long long*)(ap + 16384 + (p + 1) * 2);
      nx2 = *(const unsigned long long*)(ap + 32768 + (p + 1) * 2);
      nx3 = *(const unsigned long long*)(ap + 49152 + (p + 1) * 2);
    }
    int s0 = 2 * p;
    // ---- substep even: compute buf0 (low dwords), stage step s0+1 -> buf1 ----
#pragma unroll
    for (int c = 0; c < 6; c++)
      rg[c] = *(const i32x4*)(sp[c] + (size_t)(s0 + 1) * 8192);
    AGG_STEP(0, 0)
    AGG_STAGE_WRITE(1)
    __syncthreads();
    // ---- substep odd: compute buf1 (high dwords), stage step s0+2 -> buf0 ----
    if (p < 31) {
#pragma unroll
      for (int c = 0; c < 6; c++)
        rg[c] = *(const i32x4*)(sp[c] + (size_t)(s0 + 2) * 8192);
    }
    AGG_STEP(1, 1)
    if (p < 31) {
      AGG_STAGE_WRITE(0)
    }
    cc0 = nx0; cc1 = nx1; cc2 = nx2; cc3 = nx3;
    __syncthreads();
  }
  // epilogue: C/D 32x32 layout col=lane&31, row=(reg&3)+8*(reg>>2)+4*q
#pragma unroll
  for (int mt = 0; mt < 4; mt++)
#pragma unroll
    for (int nt = 0; nt < 2; nt++) {
      int col = wn * 64 + nt * 32 + l32;
      int rowb = rb * 128 + mt * 32 + 4 * q;
#pragma unroll
      for (int r = 0; r < 16; r++) {
        int row = rowb + (r & 3) + 8 * (r >> 2);
        atomicAdd(out + (size_t)row * 256 + col, acc[mt][nt][r]);
      }
    }
#undef AGG_MT
#undef AGG_TY
#undef AGG_STEP
#undef AGG_STAGE_WRITE
}

extern "C" void kernel_launch(void* const* d_in, const int* in_sizes, int n_in,
                              void* d_out, int out_size, void* d_ws,
                              size_t ws_size, hipStream_t stream) {
  const float* V = (const float*)d_in[0];
  const int* adj = (const int*)d_in[1];
  const float* w1 = (const float*)d_in[2];
  const float* w2 = (const float*)d_in[3];
  const float* w3 = (const float*)d_in[4];
  const float* bias = (const float*)d_in[5];
  float* out = (float*)d_out;
  // workspace layout:
  unsigned short* Bp = (unsigned short*)d_ws;                       // 12.58 MB @ 0
  unsigned char* adj2b = (unsigned char*)d_ws + 0xC00000;           // 16 MB
  unsigned short* Vbp = (unsigned short*)((char*)d_ws + 0x1C00000); // 4 MB
  unsigned short* Wbp = (unsigned short*)((char*)d_ws + 0x2000000); // 0.375 MB
  // total required: 0x2060000 = 33.9 MB

  k_prep<<<dim3(2048), dim3(256), 0, stream>>>(adj, V, w1, w2, w3, bias, adj2b,
                                               Vbp, Wbp, out);
  k_transform<<<dim3(768), dim3(256), 0, stream>>>(Vbp, Wbp, Bp);
  k_agg<<<dim3(512), dim3(256), 0, stream>>>((const unsigned*)adj2b, Bp, out);
}

// Round 8
// 491.488 us; speedup vs baseline: 1.0961x; 1.0961x over previous
//
#include <hip/hip_runtime.h>

typedef __attribute__((ext_vector_type(4))) float f32x4;
typedef __attribute__((ext_vector_type(16))) float f32x16;
typedef __attribute__((ext_vector_type(4))) unsigned short u16x4;
typedef __attribute__((ext_vector_type(4))) int i32x4;
typedef __attribute__((ext_vector_type(8))) __bf16 bf16x8;

union FragAB {
  u16x4 u[2];
  i32x4 v;
  bf16x8 f;
};

static __device__ __forceinline__ unsigned short f2bf(float x) {
  union { float f; unsigned u; } v;
  v.f = x;
  unsigned r = v.u + 0x7FFFu + ((v.u >> 16) & 1u);  // round-to-nearest-even
  return (unsigned short)(r >> 16);
}

#define NN 8192

// ---------- kernel 1: prep (unchanged, verified) ----------
__global__ __launch_bounds__(256) void k_prep(
    const int* __restrict__ adj, const float* __restrict__ V,
    const float* __restrict__ w1, const float* __restrict__ w2,
    const float* __restrict__ w3, const float* __restrict__ bias,
    unsigned char* __restrict__ adj2b, unsigned short* __restrict__ Vbp,
    unsigned short* __restrict__ Wbp, float* __restrict__ out) {
  int t = blockIdx.x * 256 + threadIdx.x;
  int nT = gridDim.x * 256;
  for (int g = t; g < 16777216; g += nT) {
    i32x4 a = *(const i32x4*)(adj + (size_t)g * 4);
    adj2b[g] = (unsigned char)((a.x & 3) | ((a.y & 3) << 2) |
                               ((a.z & 3) << 4) | ((a.w & 3) << 6));
  }
  for (int g = t; g < 524288; g += nT) {
    int f = g * 4;
    int row = f >> 8, kcol = f & 255;
    f32x4 x = *(const f32x4*)(V + (size_t)f);
    u16x4 h;
    h.x = f2bf(x.x); h.y = f2bf(x.y); h.z = f2bf(x.z); h.w = f2bf(x.w);
    *(u16x4*)(Vbp + (size_t)(kcol >> 3) * 65536 + (size_t)row * 8 + (kcol & 7)) = h;
  }
  for (int e = t; e < 65536; e += nT) {
    int k = e >> 8, n = e & 255;
    Wbp[(size_t)(k >> 3) * 6144 + (size_t)(0 * 256 + n) * 8 + (k & 7)] = f2bf(w1[e]);
  }
  for (int e = t; e < 65536; e += nT) {
    int k = e >> 8, n = e & 255;
    Wbp[(size_t)(k >> 3) * 6144 + (size_t)(1 * 256 + n) * 8 + (k & 7)] = f2bf(w2[e]);
  }
  for (int e = t; e < 65536; e += nT) {
    int k = e >> 8, n = e & 255;
    Wbp[(size_t)(k >> 3) * 6144 + (size_t)(2 * 256 + n) * 8 + (k & 7)] = f2bf(w3[e]);
  }
  for (int g = t; g < 524288; g += nT) {
    *(f32x4*)(out + (size_t)g * 4) = *(const f32x4*)(bias + ((g * 4) & 255));
  }
}

// ---------- kernel 2: Bp = (V @ Wcat)^T, reg GEMM (unchanged, verified) ----------
// Bp element (ty, n, j) at  ty*2097152 + (j>>4)*4096 + n*16 + (j&15).
__global__ __launch_bounds__(256) void k_transform(
    const unsigned short* __restrict__ Vbp, const unsigned short* __restrict__ Wbp,
    unsigned short* __restrict__ Bp) {
  int bx = blockIdx.x;
  int rb = bx & 127, nb = bx >> 7;
  int tid = threadIdx.x, lane = tid & 63;
  int wv = tid >> 6;
  int wr = wv >> 1, wc = wv & 1;
  int q = lane >> 4, l16 = lane & 15;

  f32x4 acc[2][4];
#pragma unroll
  for (int i = 0; i < 2; i++)
#pragma unroll
    for (int j = 0; j < 4; j++) acc[i][j] = (f32x4)0.0f;

  int r0 = rb * 64 + wr * 32 + l16;
  int n0 = nb * 128 + wc * 64 + l16;
  const unsigned short* av = Vbp + (size_t)q * 65536 + (size_t)r0 * 8;
  const unsigned short* bv = Wbp + (size_t)q * 6144 + (size_t)n0 * 8;

#pragma unroll 2
  for (int kk = 0; kk < 256; kk += 32) {
    FragAB af[2], bf[4];
#pragma unroll
    for (int mt = 0; mt < 2; mt++)
      af[mt].v = *(const i32x4*)(av + (size_t)(kk >> 3) * 65536 + mt * 128);
#pragma unroll
    for (int nt = 0; nt < 4; nt++)
      bf[nt].v = *(const i32x4*)(bv + (size_t)(kk >> 3) * 6144 + nt * 128);
#pragma unroll
    for (int mt = 0; mt < 2; mt++)
#pragma unroll
      for (int nt = 0; nt < 4; nt++)
        acc[mt][nt] = __builtin_amdgcn_mfma_f32_16x16x32_bf16(
            af[mt].f, bf[nt].f, acc[mt][nt], 0, 0, 0);
  }
#pragma unroll
  for (int mt = 0; mt < 2; mt++)
#pragma unroll
    for (int nt = 0; nt < 4; nt++) {
      int n = n0 + nt * 16;
      int ty = n >> 8, nn = n & 255;
      int j0 = rb * 64 + wr * 32 + mt * 16 + q * 4;
      u16x4 hv;
      hv.x = f2bf(acc[mt][nt].x);
      hv.y = f2bf(acc[mt][nt].y);
      hv.z = f2bf(acc[mt][nt].z);
      hv.w = f2bf(acc[mt][nt].w);
      size_t idx = (size_t)ty * 2097152 + (size_t)(j0 >> 4) * 4096 + nn * 16 + (j0 & 15);
      *(u16x4*)(Bp + idx) = hv;
    }
}

// ---------- kernel 3: out += sum_k (adj==k) @ H_k ----------
// v9 = v6 (verified structure: wave = 64 rows x 128 cols, mt=2/nt=4, no LDS,
// no barriers, 1-step adj reg-prefetch) + SOFTWARE-PIPELINED B-feed:
// each step's 24 loads split into 6 chunks of 4 frags (ty,kh); 3 rotating
// chunk buffers (48 VGPR, same peak as v6's single live batch); chunk m+2
// issued while chunk m computes -> ~350 cyc of mask-VALU+MFMA covers the L2
// round trip that v6 exposed twice per step. Pointers advance mid-step
// (after the last current-step issue) so next-step issues use imm offsets.
// Grid 64 rb x 8 ks = 512 blocks (2/CU); ks = bx&7 -> per-XCD L2 k-slice.
__global__ __launch_bounds__(256, 2) void k_agg(const unsigned* __restrict__ adj2,
                                                const unsigned short* __restrict__ Bp,
                                                float* __restrict__ out) {
  int bx = blockIdx.x;
  int ks = bx & 7, rb = bx >> 3;
  int tid = threadIdx.x, lane = tid & 63;
  int wv = tid >> 6;
  int wm = wv >> 1, wn = wv & 1;  // wm: 64-row slab, wn: 128-col slab
  int q = lane >> 5, l32 = lane & 31;
  int qsh = q << 4;

  f32x16 acc[2][4];
#pragma unroll
  for (int mt = 0; mt < 2; mt++)
#pragma unroll
    for (int nt = 0; nt < 4; nt++) acc[mt][nt] = (f32x16)0.0f;

  // adj2 rows for this lane's two 32-row MFMA slabs (verified v6 addressing)
  int r0 = rb * 128 + wm * 64 + l32;
  const unsigned* ap0 = adj2 + (size_t)r0 * 512 + ks * 64;
  const unsigned* ap1 = ap0 + 32 * 512;

  // 6 B-pointers [ty][kh]; elem = ty*2097152 + (ks*64+kh)*4096 + n*16 + q*8
  int nbase = (wn * 128 + l32) * 16 + q * 8;
  const unsigned short* bb[3][2];
#pragma unroll
  for (int ty = 0; ty < 3; ty++)
#pragma unroll
    for (int kh = 0; kh < 2; kh++)
      bb[ty][kh] = Bp + (size_t)ty * 2097152 + ((size_t)ks * 64 + kh) * 4096 + nbase;

  unsigned long long c0 = *(const unsigned long long*)ap0;
  unsigned long long c1 = *(const unsigned long long*)ap1;

  FragAB ch[3][4];  // rotating chunk buffers (slots 0..2)

#define AGG_ISSUE(SLOT, TY, KH)                                                \
  {                                                                            \
    _Pragma("unroll") for (int nt = 0; nt < 4; nt++)                           \
        ch[SLOT][nt].v = *(const i32x4*)(bb[TY][KH] + nt * 512);               \
  }

  // A-build + 8 MFMAs for chunk (SLOT holds B-frags of (TY, HI))
#define AGG_COMPUTE(SLOT, TY, HI)                                              \
  {                                                                            \
    unsigned w0 = (unsigned)(HI ? (c0 >> 32) : c0) >> qsh;                     \
    unsigned w1 = (unsigned)(HI ? (c1 >> 32) : c1) >> qsh;                     \
    FragAB A0, A1;                                                             \
    _Pragma("unroll") for (int d = 0; d < 4; d++) {                            \
      unsigned p00 = (w0 >> (4 * d)) & 3u, p01 = (w0 >> (4 * d + 2)) & 3u;     \
      unsigned p10 = (w1 >> (4 * d)) & 3u, p11 = (w1 >> (4 * d + 2)) & 3u;     \
      A0.v[d] = (int)((p00 == (unsigned)(TY + 1) ? 0x3F80u : 0u) |             \
                      (p01 == (unsigned)(TY + 1) ? 0x3F800000u : 0u));         \
      A1.v[d] = (int)((p10 == (unsigned)(TY + 1) ? 0x3F80u : 0u) |             \
                      (p11 == (unsigned)(TY + 1) ? 0x3F800000u : 0u));         \
    }                                                                          \
    _Pragma("unroll") for (int nt = 0; nt < 4; nt++) {                         \
      acc[0][nt] = __builtin_amdgcn_mfma_f32_32x32x16_bf16(                    \
          A0.f, ch[SLOT][nt].f, acc[0][nt], 0, 0, 0);                          \
      acc[1][nt] = __builtin_amdgcn_mfma_f32_32x32x16_bf16(                    \
          A1.f, ch[SLOT][nt].f, acc[1][nt], 0, 0, 0);                          \
    }                                                                          \
  }

  // prologue: issue step-0 chunks 0 (ty0,kh0) and 1 (ty1,kh0)
  AGG_ISSUE(0, 0, 0)
  AGG_ISSUE(1, 1, 0)

  for (int step = 0; step < 32; ++step) {
    unsigned long long nx0 = 0, nx1 = 0;
    if (step < 31) {  // next step's adj codes (imm-offset loads)
      nx0 = *(const unsigned long long*)(ap0 + 2 * (step + 1));
      nx1 = *(const unsigned long long*)(ap1 + 2 * (step + 1));
    }
    // p0: compute (ty0,kh0) | issue (ty2,kh0)
    AGG_COMPUTE(0, 0, 0)
    AGG_ISSUE(2, 2, 0)
    // p1: compute (ty1,kh0) | issue (ty0,kh1)
    AGG_COMPUTE(1, 1, 0)
    AGG_ISSUE(0, 0, 1)
    // p2: compute (ty2,kh0) | issue (ty1,kh1)
    AGG_COMPUTE(2, 2, 0)
    AGG_ISSUE(1, 1, 1)
    // p3: compute (ty0,kh1) | issue (ty2,kh1), then advance pointers
    AGG_COMPUTE(0, 0, 1)
    AGG_ISSUE(2, 2, 1)
#pragma unroll
    for (int ty = 0; ty < 3; ty++)
#pragma unroll
      for (int kh = 0; kh < 2; kh++) bb[ty][kh] += 8192;
    // p4: compute (ty1,kh1) | issue next step (ty0,kh0) via advanced ptrs
    AGG_COMPUTE(1, 1, 1)
    if (step < 31) {
      AGG_ISSUE(0, 0, 0)
    }
    // p5: compute (ty2,kh1) | issue next step (ty1,kh0)
    AGG_COMPUTE(2, 2, 1)
    if (step < 31) {
      AGG_ISSUE(1, 1, 0)
    }
    c0 = nx0;
    c1 = nx1;
  }
#undef AGG_ISSUE
#undef AGG_COMPUTE
  // epilogue: C/D 32x32 layout col=lane&31, row=(reg&3)+8*(reg>>2)+4*q
#pragma unroll
  for (int mt = 0; mt < 2; mt++)
#pragma unroll
    for (int nt = 0; nt < 4; nt++) {
      int col = wn * 128 + nt * 32 + l32;
      int rowb = rb * 128 + wm * 64 + mt * 32 + 4 * q;
#pragma unroll
      for (int r = 0; r < 16; r++) {
        int row = rowb + (r & 3) + 8 * (r >> 2);
        atomicAdd(out + (size_t)row * 256 + col, acc[mt][nt][r]);
      }
    }
}

extern "C" void kernel_launch(void* const* d_in, const int* in_sizes, int n_in,
                              void* d_out, int out_size, void* d_ws,
                              size_t ws_size, hipStream_t stream) {
  const float* V = (const float*)d_in[0];
  const int* adj = (const int*)d_in[1];
  const float* w1 = (const float*)d_in[2];
  const float* w2 = (const float*)d_in[3];
  const float* w3 = (const float*)d_in[4];
  const float* bias = (const float*)d_in[5];
  float* out = (float*)d_out;
  // workspace layout:
  unsigned short* Bp = (unsigned short*)d_ws;                       // 12.58 MB @ 0
  unsigned char* adj2b = (unsigned char*)d_ws + 0xC00000;           // 16 MB
  unsigned short* Vbp = (unsigned short*)((char*)d_ws + 0x1C00000); // 4 MB
  unsigned short* Wbp = (unsigned short*)((char*)d_ws + 0x2000000); // 0.375 MB
  // total required: 0x2060000 = 33.9 MB

  k_prep<<<dim3(2048), dim3(256), 0, stream>>>(adj, V, w1, w2, w3, bias, adj2b,
                                               Vbp, Wbp, out);
  k_transform<<<dim3(768), dim3(256), 0, stream>>>(Vbp, Wbp, Bp);
  k_agg<<<dim3(512), dim3(256), 0, stream>>>((const unsigned*)adj2b, Bp, out);
}